// Round 2
// baseline (384.477 us; speedup 1.0000x reference)
//
#include <hip/hip_runtime.h>

#define KG_E   200000
#define IN_DIM 256
#define OUT_DIM 128
#define BATCH  20000
#define NEDGE  640000
#define BUCKET 128   // padded slots per row; degree ~Bin(620K,1/20K): mu=32, sd=5.6

typedef unsigned short ushort_t;
typedef __attribute__((ext_vector_type(8))) short bf16x8;   // 8 bf16 = 4 VGPRs
typedef __attribute__((ext_vector_type(4))) float f32x4;
typedef __attribute__((ext_vector_type(4))) int   i32x4;

__device__ __forceinline__ float bf2f(unsigned int u) {
  return __builtin_bit_cast(float, u << 16);
}
__device__ __forceinline__ unsigned short f2bf(float f) {
  unsigned int x = __builtin_bit_cast(unsigned int, f);
  x += 0x7FFFu + ((x >> 16) & 1u);   // round-to-nearest-even
  return (unsigned short)(x >> 16);
}
__device__ __forceinline__ int idx_at(const void* p, long long i, int is64) {
  return is64 ? (int)((const long long*)p)[i] : ((const int*)p)[i];
}
__device__ __forceinline__ float fld(const void* p, int i, int isf32) {
  return isf32 ? ((const float*)p)[i] : bf2f(((const ushort_t*)p)[i]);
}
__device__ __forceinline__ bf16x8 pack8(f32x4 a, f32x4 b) {
  bf16x8 r;
#pragma unroll
  for (int j = 0; j < 4; j++) {
    ((ushort_t*)&r)[j]     = f2bf(a[j]);
    ((ushort_t*)&r)[4 + j] = f2bf(b[j]);
  }
  return r;
}

// ---------------------------------------------------------------------------
// Per-wave dtype detection (replaces the detect dispatch). Every wave samples
// the same leading 1KB (L1/L2-hot) and reaches an identical verdict via
// ballot, so no LDS broadcast or cross-kernel flag buffer is needed.
// ---------------------------------------------------------------------------
__device__ __forceinline__ int detect_f32_wave(const void* ent) {
  int lane = threadIdx.x & 63;
  const ushort_t* u = (const ushort_t*)ent;
  int cnt = 0;
#pragma unroll
  for (int i = 0; i < 4; i++) {
    int e = (u[2 * (lane * 4 + i)] >> 7) & 0xff;
    cnt += __popcll(__ballot(e >= 113 && e <= 141));
  }
  return (cnt >= 128) ? 0 : 1;   // plausible-bf16 majority -> not fp32
}
__device__ __forceinline__ int detect_i64_wave(const void* edge) {
  int lane = threadIdx.x & 63;
  int nz = ((const int*)edge)[2 * lane + 1] != 0;
  return (__ballot(nz) == 0ULL) ? 1 : 0;   // all upper words zero -> int64
}

// ---------------------------------------------------------------------------
// K1: streaming GEMM, barrier-free K-loop. 512 thr / 8 waves; W staged once to
// LDS (bf16, XOR-swizzled); each wave computes 16 rows x 128 cols with 4-deep
// A-register ring prefetch. Epilogue fuses per-node scores sRn/sLn, then
// LDS-transpose for 16B stores. Blocks 0..39 also zero-fill cursor[].
// ---------------------------------------------------------------------------
__global__ __launch_bounds__(512, 4) void gemm_kernel(
    const void* __restrict__ ent, const void* __restrict__ W,
    const void* __restrict__ bias, const void* __restrict__ w_atten,
    ushort_t* __restrict__ gat, float* __restrict__ sRn, float* __restrict__ sLn,
    int* __restrict__ cursor)
{
  __shared__ __align__(16) unsigned char lds[65536];
  const int isf32 = detect_f32_wave(ent);
  const int tid  = threadIdx.x;
  const int lane = tid & 63;
  const int w    = tid >> 6;       // wave 0..7
  const int l16  = lane & 15;
  const int quad = lane >> 4;
  const int m0   = blockIdx.x * 128;

  // fused cursor zero (no memset dispatch)
  if (blockIdx.x < (BATCH + 511) / 512) {
    int zi = blockIdx.x * 512 + tid;
    if (zi < BATCH) cursor[zi] = 0;
  }

#pragma unroll
  for (int i = 0; i < 8; i++) {
    int L = i * 512 + tid;              // 16B-slot id, 0..4095
    int r = L >> 5, s = L & 31;
    bf16x8 v;
    if (isf32) {
      const float* bp = (const float*)W + r * 256 + s * 8;
      v = pack8(*(const f32x4*)bp, *(const f32x4*)(bp + 4));
    } else {
      v = *(const bf16x8*)((const ushort_t*)W + r * 256 + s * 8);
    }
    *(bf16x8*)(lds + r * 512 + ((s ^ (r & 15)) * 16)) = v;
  }
  __syncthreads();

  const int row0 = m0 + w * 16;
  int arow = row0 + l16; arow = arow < KG_E ? arow : (KG_E - 1);

  f32x4 acc[8];
#pragma unroll
  for (int nt = 0; nt < 8; nt++) acc[nt] = (f32x4){0.f, 0.f, 0.f, 0.f};

#define MFMA_STEP(AF, KS)                                                     \
  do {                                                                        \
    _Pragma("unroll") for (int nt = 0; nt < 8; nt++) {                        \
      bf16x8 bf = *(const bf16x8*)(lds + (nt * 16 + l16) * 512 +              \
                                   ((((KS) * 4 + quad) ^ l16) * 16));         \
      acc[nt] = __builtin_amdgcn_mfma_f32_16x16x32_bf16(AF, bf, acc[nt], 0, 0, 0); \
    }                                                                         \
  } while (0)

  if (isf32) {
    const float* ap = (const float*)ent + (size_t)arow * IN_DIM + quad * 8;
    f32x4 b0[4], b1[4];
#pragma unroll
    for (int p = 0; p < 4; p++) {
      b0[p] = *(const f32x4*)(ap + p * 32);
      b1[p] = *(const f32x4*)(ap + p * 32 + 4);
    }
#pragma unroll
    for (int ks = 0; ks < 8; ks++) {
      bf16x8 af = pack8(b0[ks & 3], b1[ks & 3]);
      if (ks < 4) {
        b0[ks & 3] = *(const f32x4*)(ap + (ks + 4) * 32);
        b1[ks & 3] = *(const f32x4*)(ap + (ks + 4) * 32 + 4);
      }
      MFMA_STEP(af, ks);
    }
  } else {
    const ushort_t* ap = (const ushort_t*)ent + (size_t)arow * IN_DIM + quad * 8;
    bf16x8 ab[4];
#pragma unroll
    for (int p = 0; p < 4; p++) ab[p] = *(const bf16x8*)(ap + p * 32);
#pragma unroll
    for (int ks = 0; ks < 8; ks++) {
      bf16x8 af = ab[ks & 3];
      if (ks < 4) ab[ks & 3] = *(const bf16x8*)(ap + (ks + 4) * 32);
      MFMA_STEP(af, ks);
    }
  }
#undef MFMA_STEP

  float bv[8], w1v[8], w2v[8];
#pragma unroll
  for (int nt = 0; nt < 8; nt++) {
    int c = nt * 16 + l16;
    bv[nt]  = fld(bias, c, isf32);
    w1v[nt] = fld(w_atten, c, isf32);
    w2v[nt] = fld(w_atten, OUT_DIM + c, isf32);
  }
  float pr[4] = {0.f, 0.f, 0.f, 0.f}, pl[4] = {0.f, 0.f, 0.f, 0.f};
#pragma unroll
  for (int nt = 0; nt < 8; nt++)
#pragma unroll
    for (int reg = 0; reg < 4; reg++) {
      float v = acc[nt][reg] + bv[nt];
      acc[nt][reg] = v;
      pr[reg] += v * w2v[nt];
      pl[reg] += v * w1v[nt];
    }
#pragma unroll
  for (int m = 1; m < 16; m <<= 1)
#pragma unroll
    for (int reg = 0; reg < 4; reg++) {
      pr[reg] += __shfl_xor(pr[reg], m);
      pl[reg] += __shfl_xor(pl[reg], m);
    }
  if (l16 == 0) {
#pragma unroll
    for (int reg = 0; reg < 4; reg++) {
      int r = row0 + quad * 4 + reg;
      if (r < KG_E) { sRn[r] = pr[reg]; sLn[r] = pl[reg]; }
    }
  }

  __syncthreads();
#pragma unroll
  for (int nt = 0; nt < 8; nt++)
#pragma unroll
    for (int reg = 0; reg < 4; reg++)
      *(ushort_t*)(lds + (w * 16 + quad * 4 + reg) * 272 + (nt * 16 + l16) * 2) =
          f2bf(acc[nt][reg]);
  __syncthreads();
#pragma unroll
  for (int i = 0; i < 4; i++) {
    int L = i * 512 + tid;
    int rl = L >> 4, cs = L & 15;
    int gr = m0 + rl;
    if (gr < KG_E) {
      f32x4 v = *(const f32x4*)(lds + rl * 272 + cs * 16);
      *(f32x4*)((char*)gat + (size_t)gr * 256 + cs * 16) = v;
    }
  }
}

// ---------------------------------------------------------------------------
// K2: direct-bucket scatter, 2 edges/thread (adjacent index loads merge into
// dwordx4). Per edge: gather batch_ids[row] -> sLn, sRn[col]; attention; claim
// a slot in the row's 128-wide padded bucket with one atomic.
// ---------------------------------------------------------------------------
__global__ __launch_bounds__(256) void scatter_kernel(
    const void* __restrict__ edge, const void* __restrict__ batch_ids,
    const float* __restrict__ sLn, const float* __restrict__ sRn,
    int* __restrict__ cursor, int2* __restrict__ colatt)
{
  const int is64 = detect_i64_wave(edge);
  long long e = (long long)(blockIdx.x * 256 + threadIdx.x) * 2;
  if (e >= NEDGE) return;
#pragma unroll
  for (int t = 0; t < 2; t++) {
    int r = idx_at(edge, e + t, is64);
    r = r < 0 ? 0 : (r >= BATCH ? BATCH - 1 : r);
    int c = idx_at(edge, (long long)NEDGE + e + t, is64);
    c = c < 0 ? 0 : (c >= KG_E ? KG_E - 1 : c);
    int b = idx_at(batch_ids, r, is64);
    b = b < 0 ? 0 : (b >= KG_E ? KG_E - 1 : b);
    float score = sLn[b] + sRn[c];
    float lr = score > 0.f ? score : 0.2f * score;
    lr = lr > 80.f ? 80.f : (lr < -80.f ? -80.f : lr);
    float att = __expf(-lr);
    int p = atomicAdd(&cursor[r], 1);
    if (p < BUCKET)
      colatt[(size_t)r * BUCKET + p] = make_int2(c, __builtin_bit_cast(int, att));
  }
}

// ---------------------------------------------------------------------------
// K3: one wave per batch row, quad-per-edge: quad q of the wave handles edge
// j+q, each lane gathers 16B (8 bf16 cols). One gather (1KB/wave-instr, peak
// width) + one broadcast slot-pair load per 4 edges -> half the VMEM
// instructions of the half-wave version. Quad partials combined via
// shfl_xor(16|32); lanes 0-15 store 32B each.
// ---------------------------------------------------------------------------
__global__ __launch_bounds__(256) void aggregate_kernel(
    const ushort_t* __restrict__ gat, const int* __restrict__ colatt,
    const int* __restrict__ cursor, const void* __restrict__ prelu,
    const void* __restrict__ ent, float* __restrict__ out)
{
  const int isf32 = detect_f32_wave(ent);
  const int row  = __builtin_amdgcn_readfirstlane(blockIdx.x * 4 + (threadIdx.x >> 6));
  const int lane = threadIdx.x & 63;
  const int quad = lane >> 4;        // edge j+quad within a 4-group
  const int l16  = lane & 15;        // cols 8*l16 .. 8*l16+7
  int cnt = __builtin_amdgcn_readfirstlane(cursor[row]);
  cnt = cnt < BUCKET ? cnt : BUCKET;
  const i32x4* ca4 = (const i32x4*)(colatt + (size_t)row * (BUCKET * 2));

  float acc[8] = {0.f, 0.f, 0.f, 0.f, 0.f, 0.f, 0.f, 0.f};
  float rowsum = 0.f;

  // GUARD=0 in the steady loop: no clamp, no tail compare in the hot path.
#define DO4(J, GUARD)                                                          \
  do {                                                                         \
    i32x4 q_ = ca4[((J) >> 1) + (quad >> 1)];                                  \
    int   c_ = (quad & 1) ? q_.z : q_.x;                                       \
    float a_ = __builtin_bit_cast(float, (quad & 1) ? q_.w : q_.y);            \
    if (GUARD) {                                                               \
      if ((J) + quad >= cnt) a_ = 0.f;                                         \
      c_ = c_ < 0 ? 0 : (c_ >= KG_E ? KG_E - 1 : c_);                          \
    }                                                                          \
    bf16x8 g_ = *(const bf16x8*)(gat + (size_t)c_ * OUT_DIM + l16 * 8);        \
    _Pragma("unroll") for (int k = 0; k < 8; k++)                              \
        acc[k] += a_ * bf2f(((const ushort_t*)&g_)[k]);                        \
    rowsum += a_;                                                              \
  } while (0)

  int j = 0;
  for (; j + 8 <= cnt; j += 8) { DO4(j, 0); DO4(j + 4, 0); }
  for (; j < cnt; j += 4) DO4(j, 1);
#undef DO4

#pragma unroll
  for (int m = 16; m <= 32; m <<= 1) {
#pragma unroll
    for (int k = 0; k < 8; k++) acc[k] += __shfl_xor(acc[k], m);
    rowsum += __shfl_xor(rowsum, m);
  }

  if (quad == 0) {
    float inv = rowsum > 0.f ? 1.0f / rowsum : 0.f;
    float pw = fld(prelu, 0, isf32);
    f32x4 v0, v1;
#pragma unroll
    for (int k = 0; k < 4; k++) {
      float t = acc[k] * inv;
      v0[k] = t >= 0.f ? t : pw * t;
    }
#pragma unroll
    for (int k = 0; k < 4; k++) {
      float t = acc[4 + k] * inv;
      v1[k] = t >= 0.f ? t : pw * t;
    }
    float* op = out + (size_t)row * OUT_DIM + l16 * 8;
    *(f32x4*)op = v0;
    *(f32x4*)(op + 4) = v1;
  }
}

// ---------------------------------------------------------------------------
extern "C" void kernel_launch(void* const* d_in, const int* in_sizes, int n_in,
                              void* d_out, int out_size, void* d_ws, size_t ws_size,
                              hipStream_t stream) {
  const void* ent       = d_in[0];
  const void* batch_ids = d_in[1];
  const void* edge      = d_in[2];
  const void* W         = d_in[3];
  const void* bias      = d_in[4];
  const void* w_atten   = d_in[5];
  const void* prelu     = d_in[6];
  float*      out       = (float*)d_out;

  char* p = (char*)d_ws;
  ushort_t* gat  = (ushort_t*)p;  p += (size_t)KG_E * OUT_DIM * 2;  // 51.2 MB
  float* sRn     = (float*)p;     p += (size_t)KG_E * 4;            // 800 KB
  float* sLn     = (float*)p;     p += (size_t)KG_E * 4;            // 800 KB
  int* cursor    = (int*)p;       p += (size_t)BATCH * 4;           // 80 KB
  p = (char*)(((size_t)p + 15) & ~(size_t)15);
  int2* colatt   = (int2*)p;      p += (size_t)BATCH * BUCKET * 8;  // 20.5 MB

  gemm_kernel<<<dim3((KG_E + 127) / 128), dim3(512), 0, stream>>>(
      ent, W, bias, w_atten, gat, sRn, sLn, cursor);
  scatter_kernel<<<dim3(NEDGE / 512), dim3(256), 0, stream>>>(
      edge, batch_ids, sLn, sRn, cursor, colatt);
  aggregate_kernel<<<dim3(BATCH / 4), dim3(256), 0, stream>>>(
      gat, (const int*)colatt, cursor, prelu, ent, out);
}